// Round 1
// baseline (2493.192 us; speedup 1.0000x reference)
//
#include <hip/hip_runtime.h>
#include <math.h>

#define BATCH 32
#define FIN   8192
#define FOUT  16384
#define HEADS 512
#define KSPLIT 4
#define KRANGE (FIN / KSPLIT)   // 2048

// ---------------------------------------------------------------------------
// K2: skinny GEMM  acc[b][o] = sum_k x[b][k] * W[o][k], K-split over blockIdx.y
// One output feature per thread; 32 batch accumulators in VGPRs; x is
// block-uniform -> scalar (s_load) operand; W streamed as float4 (128B/lane
// per iteration so every cacheline is fully consumed). Partials combined with
// fp32 global atomicAdd (4 contributors per address).
// ---------------------------------------------------------------------------
__global__ __launch_bounds__(256) void gemm_kernel(
    const float* __restrict__ x,
    const float* __restrict__ Wq, const float* __restrict__ Wk,
    const float* __restrict__ Wv,
    float* __restrict__ qkv)
{
    const int mat = blockIdx.z;
    const float* W = (mat == 0) ? Wq : (mat == 1 ? Wk : Wv);
    const int o  = blockIdx.x * 256 + threadIdx.x;
    const int k0 = blockIdx.y * KRANGE;

    const float4* Wp = (const float4*)(W + (size_t)o * FIN + k0);
    const float*  xp = x + k0;

    float acc[BATCH];
#pragma unroll
    for (int b = 0; b < BATCH; ++b) acc[b] = 0.f;

    for (int kk = 0; kk < KRANGE / 4; kk += 8) {   // 32 k-floats per iter
        float4 w[8];
#pragma unroll
        for (int u = 0; u < 8; ++u) w[u] = Wp[kk + u];
#pragma unroll
        for (int u = 0; u < 8; ++u) {
            const int kb = (kk + u) * 4;
#pragma unroll
            for (int b = 0; b < BATCH; ++b) {
                const float* xb = xp + b * FIN + kb;   // block-uniform -> SGPR
                float a = acc[b];
                a = fmaf(w[u].x, xb[0], a);
                a = fmaf(w[u].y, xb[1], a);
                a = fmaf(w[u].z, xb[2], a);
                a = fmaf(w[u].w, xb[3], a);
                acc[b] = a;
            }
        }
    }

    float* outp = qkv + (size_t)mat * (BATCH * FOUT) + o;
#pragma unroll
    for (int b = 0; b < BATCH; ++b)
        atomicAdd(outp + (size_t)b * FOUT, acc[b]);
}

// ---------------------------------------------------------------------------
// K3: bias + exact GELU (erf), float4-vectorized, in place on qkv
// ---------------------------------------------------------------------------
__device__ __forceinline__ float gelu_exact(float z)
{
    return 0.5f * z * (1.f + erff(z * 0.70710678118654752f));
}

__global__ __launch_bounds__(256) void bias_gelu_kernel(
    float* __restrict__ qkv,
    const float* __restrict__ bq, const float* __restrict__ bk,
    const float* __restrict__ bv)
{
    const int total4 = 3 * BATCH * FOUT / 4;
    int idx = blockIdx.x * 256 + threadIdx.x;
    if (idx >= total4) return;
    const int per_mat4 = BATCH * FOUT / 4;
    int mat = idx / per_mat4;
    int r   = idx - mat * per_mat4;
    int o4  = r & (FOUT / 4 - 1);
    const float* bias = (mat == 0) ? bq : (mat == 1 ? bk : bv);
    float4 v  = ((const float4*)qkv)[idx];
    float4 bb = ((const float4*)bias)[o4];
    v.x = gelu_exact(v.x + bb.x);
    v.y = gelu_exact(v.y + bb.y);
    v.z = gelu_exact(v.z + bb.z);
    v.w = gelu_exact(v.w + bb.w);
    ((float4*)qkv)[idx] = v;
}

// ---------------------------------------------------------------------------
// K4: attention with softmax over the HEADS axis.
// bias[i,j] is constant along the softmax axis -> cancels exactly; tw unused.
// Block = (i, b). Pass 1: Z[j] = sum_h exp(c*q[h,i]*k[h,j]); pass 2:
// out[b,h,i] = sum_j exp(c*q[h,i]*k[h,j]) * v[h,j] / Z[j].
// No max-subtraction: |scores| <= ~5 -> exp safely in fp32 range.
// ---------------------------------------------------------------------------
__global__ __launch_bounds__(256) void attn_kernel(
    const float* __restrict__ qkv, float* __restrict__ out)
{
    const float* Q = qkv;
    const float* K = qkv + (size_t)BATCH * FOUT;
    const float* V = qkv + (size_t)2 * BATCH * FOUT;

    const int i = blockIdx.x;
    const int b = blockIdx.y;
    const int t = threadIdx.x;
    const float c = 0.17677669529663688f;   // 1/sqrt(32)

    __shared__ float zpart[8][32];
    __shared__ float rz[32];

    // pass 1: partial Z over 64-head chunks
    {
        const int j = t & 31, hg = t >> 5;
        const float* qb = Q + (size_t)b * FOUT + i;   // + h*32 (uniform loads)
        const float* kb = K + (size_t)b * FOUT + j;
        float zs = 0.f;
        for (int h = hg * 64; h < hg * 64 + 64; ++h) {
            float qv = qb[h * 32];
            float kv = kb[h * 32];
            zs += __expf(c * qv * kv);
        }
        zpart[hg][j] = zs;
    }
    __syncthreads();
    if (t < 32) {
        float z = 0.f;
#pragma unroll
        for (int g = 0; g < 8; ++g) z += zpart[g][t];
        rz[t] = 1.f / z;
    }
    __syncthreads();

    // pass 2: two head-rows per thread
#pragma unroll
    for (int rep = 0; rep < 2; ++rep) {
        const int h = t + rep * 256;
        const float qv = Q[(size_t)b * FOUT + h * 32 + i];
        const float4* krow = (const float4*)(K + (size_t)b * FOUT + h * 32);
        const float4* vrow = (const float4*)(V + (size_t)b * FOUT + h * 32);
        float acc = 0.f;
#pragma unroll
        for (int j4 = 0; j4 < 8; ++j4) {
            float4 kv = krow[j4];
            float4 vv = vrow[j4];
            acc += __expf(c * qv * kv.x) * rz[j4 * 4 + 0] * vv.x;
            acc += __expf(c * qv * kv.y) * rz[j4 * 4 + 1] * vv.y;
            acc += __expf(c * qv * kv.z) * rz[j4 * 4 + 2] * vv.z;
            acc += __expf(c * qv * kv.w) * rz[j4 * 4 + 3] * vv.w;
        }
        out[(size_t)b * FOUT + h * 32 + i] = acc;
    }
}

// ---------------------------------------------------------------------------
extern "C" void kernel_launch(void* const* d_in, const int* in_sizes, int n_in,
                              void* d_out, int out_size, void* d_ws, size_t ws_size,
                              hipStream_t stream)
{
    const float* x  = (const float*)d_in[0];
    const float* Wq = (const float*)d_in[1];
    const float* bq = (const float*)d_in[2];
    const float* Wk = (const float*)d_in[3];
    const float* bk = (const float*)d_in[4];
    const float* Wv = (const float*)d_in[5];
    const float* bv = (const float*)d_in[6];
    // d_in[7] = tw: unused — constant along softmax axis (heads), cancels.

    float* qkv = (float*)d_ws;               // [3][BATCH][FOUT] fp32 = 6 MB
    float* out = (float*)d_out;

    hipMemsetAsync(qkv, 0, (size_t)3 * BATCH * FOUT * sizeof(float), stream);

    gemm_kernel<<<dim3(FOUT / 256, KSPLIT, 3), 256, 0, stream>>>(x, Wq, Wk, Wv, qkv);

    const int total4 = 3 * BATCH * FOUT / 4;
    bias_gelu_kernel<<<(total4 + 255) / 256, 256, 0, stream>>>(qkv, bq, bk, bv);

    attn_kernel<<<dim3(32, BATCH), 256, 0, stream>>>(qkv, out);
}